// Round 2
// baseline (11248.292 us; speedup 1.0000x reference)
//
#include <hip/hip_runtime.h>

#define D 4096
#define NH 32
#define NKV 8
#define HD 128
#define FF 14336
#define VOC 1024
#define TT 32
#define GENN 8
#define SEQ 9

#define NQKV 6144   // fused QKV rows: 4096 Q + 1024 K + 1024 V
#define NGU  28672  // fused gate+up rows: 14336 + 14336

// workspace offsets (floats)
#define OFF_BUF   0ull                    // 32*9*4096 = 1179648
#define OFF_HT    1179648ull              // 4096*32
#define OFF_Q     1310720ull              // 32*4096
#define OFF_KC    1441792ull              // 32*9*8*128
#define OFF_VC    1736704ull
#define OFF_AOT   2031616ull              // 4096*32
#define OFF_XP    2162688ull
#define OFF_H2T   2293760ull
#define OFF_XOT   2424832ull
#define OFF_INT   2555904ull              // 14336*32
#define OFF_PART  3014656ull

__global__ void k_init(const float* __restrict__ x0, float* __restrict__ buf) {
    int i = blockIdx.x * 256 + threadIdx.x;   // T*D threads
    int t = i / D, d = i % D;
    buf[(size_t)t * SEQ * D + d] = x0[i];
}

__global__ void k_rmsnorm(const float* __restrict__ base, int rowStride,
                          const float* __restrict__ w, float* __restrict__ outT) {
    int t = blockIdx.x;
    const float* x = base + (size_t)t * rowStride;
    float ss = 0.f;
    for (int d = threadIdx.x; d < D; d += 256) { float v = x[d]; ss += v * v; }
    #pragma unroll
    for (int m = 1; m < 64; m <<= 1) ss += __shfl_xor(ss, m);
    __shared__ float red[4];
    int wid = threadIdx.x >> 6;
    if ((threadIdx.x & 63) == 0) red[wid] = ss;
    __syncthreads();
    float tot = red[0] + red[1] + red[2] + red[3];
    float r = 1.0f / sqrtf(tot / (float)D + 1e-5f);
    for (int d = threadIdx.x; d < D; d += 256)
        outT[(size_t)d * TT + t] = x[d] * r * w[d];
}

// part[split][n][m] = sum_{k in split} X[m][k] * W[n][k]
// XT is [K][32] (transposed activations, wave-uniform -> scalar loads).
// 4 waves/block; each wave = one (row-tile, split) unit; lane <-> output row.
// No LDS: W rows stream through registers as float4 (L1 covers line reuse).
__global__ __launch_bounds__(256) void k_gemm(const float* __restrict__ XT,
        const float* __restrict__ W, float* __restrict__ part,
        int N, int K, int ntiles, int kc) {
    int unit = blockIdx.x * 4 + (threadIdx.x >> 6);
    int lane = threadIdx.x & 63;
    int tile = unit % ntiles;
    int split = unit / ntiles;
    int n = tile * 64 + lane;
    int k0 = split * kc;
    const float* wrow = W + (size_t)n * K + k0;
    const float* xbase = XT + (size_t)k0 * TT;
    float acc[32];
    #pragma unroll
    for (int m = 0; m < 32; ++m) acc[m] = 0.f;
    #pragma unroll 2
    for (int kk = 0; kk < kc; kk += 4) {
        float4 wv = *(const float4*)(wrow + kk);
        const float* xk = xbase + (size_t)kk * TT;
        #pragma unroll
        for (int j = 0; j < 4; ++j) {
            float w = (j == 0) ? wv.x : (j == 1) ? wv.y : (j == 2) ? wv.z : wv.w;
            #pragma unroll
            for (int m = 0; m < 32; ++m)
                acc[m] = fmaf(xk[j * TT + m], w, acc[m]);
        }
    }
    float* dst = part + ((size_t)split * N + (size_t)n) * TT;
    #pragma unroll
    for (int m = 0; m < 32; ++m) dst[m] = acc[m];
}

// reduce fused-QKV partials (S splits), apply RoPE at position p, fill caches
__global__ void k_qkv_finish(const float* __restrict__ pQKV, float* __restrict__ q,
                             float* __restrict__ kcache, float* __restrict__ vcache,
                             int p, int S) {
    int idx = blockIdx.x * 256 + threadIdx.x;
    float fp = (float)p;
    if (idx < TT * NH * 64) {            // Q rows [0, 4096)
        int d = idx & 63, h = (idx >> 6) & 31, t = idx >> 11;
        int n0 = h * HD + d, n1 = n0 + 64;
        float a = 0.f, b = 0.f;
        for (int s = 0; s < S; ++s) {
            a += pQKV[((size_t)s * NQKV + n0) * TT + t];
            b += pQKV[((size_t)s * NQKV + n1) * TT + t];
        }
        float ang = fp * powf(500000.0f, -(float)d * (1.0f / 64.0f));
        float cs = cosf(ang), sn = sinf(ang);
        q[(size_t)t * D + n0] = a * cs - b * sn;
        q[(size_t)t * D + n1] = b * cs + a * sn;
    } else if (idx < TT * NH * 64 + TT * NKV * 64) {   // K rows [4096, 5120)
        int r = idx - TT * NH * 64;
        int d = r & 63, kvh = (r >> 6) & 7, t = r >> 9;
        int n0 = 4096 + kvh * HD + d, n1 = n0 + 64;
        float a = 0.f, b = 0.f;
        for (int s = 0; s < S; ++s) {
            a += pQKV[((size_t)s * NQKV + n0) * TT + t];
            b += pQKV[((size_t)s * NQKV + n1) * TT + t];
        }
        float ang = fp * powf(500000.0f, -(float)d * (1.0f / 64.0f));
        float cs = cosf(ang), sn = sinf(ang);
        float* krow = kcache + (((size_t)t * SEQ + p) * NKV + kvh) * HD;
        krow[d] = a * cs - b * sn;
        krow[d + 64] = b * cs + a * sn;
    } else {                                            // V rows [5120, 6144)
        int r = idx - (TT * NH * 64 + TT * NKV * 64);
        int d = r & 127, kvh = (r >> 7) & 7, t = r >> 10;
        int n = 5120 + kvh * HD + d;
        float a = 0.f;
        for (int s = 0; s < S; ++s)
            a += pQKV[((size_t)s * NQKV + n) * TT + t];
        vcache[(((size_t)t * SEQ + p) * NKV + kvh) * HD + d] = a;
    }
}

__global__ __launch_bounds__(64) void k_attn(const float* __restrict__ q,
        const float* __restrict__ kcache, const float* __restrict__ vcache,
        float* __restrict__ aoT, int p) {
    int t = blockIdx.x >> 5;
    int h = blockIdx.x & 31;
    int kvh = h >> 2;                // G = NH/NKV = 4
    int lane = threadIdx.x;
    const float* qp = q + (size_t)t * D + h * HD;
    float q0 = qp[lane], q1 = qp[lane + 64];
    const float scale = 0.08838834764831845f;  // 1/sqrt(128)
    float s[SEQ];
    float mx = -1e30f;
    #pragma unroll
    for (int j = 0; j < SEQ; ++j) {
        const float* kr = kcache + (((size_t)t * SEQ + j) * NKV + kvh) * HD;
        float ps = q0 * kr[lane] + q1 * kr[lane + 64];
        #pragma unroll
        for (int m = 1; m < 64; m <<= 1) ps += __shfl_xor(ps, m);
        ps = (j <= p) ? ps * scale : -1e30f;
        s[j] = ps;
        mx = fmaxf(mx, ps);
    }
    float denom = 0.f;
    #pragma unroll
    for (int j = 0; j < SEQ; ++j) {
        float e = expf(s[j] - mx);
        e = (j <= p) ? e : 0.f;
        s[j] = e; denom += e;
    }
    float inv = 1.0f / denom;
    float o0 = 0.f, o1 = 0.f;
    #pragma unroll
    for (int j = 0; j < SEQ; ++j) {
        const float* vr = vcache + (((size_t)t * SEQ + j) * NKV + kvh) * HD;
        float w = s[j] * inv;
        o0 = fmaf(w, vr[lane], o0);
        o1 = fmaf(w, vr[lane + 64], o1);
    }
    aoT[(size_t)(h * HD + lane) * TT + t] = o0;
    aoT[(size_t)(h * HD + lane + 64) * TT + t] = o1;
}

__global__ void k_reduce_o(const float* __restrict__ part, const float* __restrict__ buf,
                           float* __restrict__ xp, int p, int S) {
    int idx = blockIdx.x * 256 + threadIdx.x;   // D*32
    int n = idx >> 5, t = idx & 31;
    float a = 0.f;
    for (int s = 0; s < S; ++s) a += part[(size_t)s * D * TT + idx];
    xp[(size_t)t * D + n] = a + buf[((size_t)t * SEQ + p) * D + n];
}

__global__ void k_silu_mul(const float* __restrict__ pGU, float* __restrict__ outT, int S) {
    int idx = blockIdx.x * 256 + threadIdx.x;   // FF*32, idx = n*32 + t
    float g = 0.f, u = 0.f;
    for (int s = 0; s < S; ++s) {
        g += pGU[(size_t)s * NGU * TT + idx];
        u += pGU[(size_t)s * NGU * TT + (size_t)FF * TT + idx];
    }
    float sg = g / (1.0f + expf(-g));
    outT[idx] = sg * u;
}

__global__ void k_reduce_d(const float* __restrict__ part, const float* __restrict__ xp,
                           float* __restrict__ xoT, int S) {
    int idx = blockIdx.x * 256 + threadIdx.x;   // D*32
    int n = idx >> 5, t = idx & 31;
    float a = 0.f;
    for (int s = 0; s < S; ++s) a += part[(size_t)s * D * TT + idx];
    xoT[idx] = a + xp[(size_t)t * D + n];
}

__global__ void k_head(const float* __restrict__ part, const float* __restrict__ bias,
                       const float* __restrict__ emb, int* __restrict__ toks,
                       float* __restrict__ buf, int p, int S) {
    int t = blockIdx.x;
    int tid = threadIdx.x;
    float bv = -1e30f; int bi = 0;
    for (int n = tid; n < VOC; n += 256) {
        float a = bias[n];
        for (int s = 0; s < S; ++s) a += part[((size_t)s * VOC + n) * TT + t];
        if (a > bv) { bv = a; bi = n; }   // ascending n -> first max kept
    }
    __shared__ float sv[256];
    __shared__ int si[256];
    sv[tid] = bv; si[tid] = bi;
    __syncthreads();
    for (int off = 128; off > 0; off >>= 1) {
        if (tid < off) {
            float v2 = sv[tid + off]; int i2 = si[tid + off];
            if (v2 > sv[tid] || (v2 == sv[tid] && i2 < si[tid])) { sv[tid] = v2; si[tid] = i2; }
        }
        __syncthreads();
    }
    int tok = si[0];
    if (tid == 0) toks[t * GENN + p] = tok;
    const float* er = emb + (size_t)tok * D;
    float* brow = buf + ((size_t)t * SEQ + (p + 1)) * D;
    for (int d = tid; d < D; d += 256) brow[d] = er[d];
}

extern "C" void kernel_launch(void* const* d_in, const int* in_sizes, int n_in,
                              void* d_out, int out_size, void* d_ws, size_t ws_size,
                              hipStream_t stream) {
    const float* x0   = (const float*)d_in[0];
    const float* Wq   = (const float*)d_in[1];   // [4096, 4096] — NOTE: fused QKV assumes
    const float* Wk   = (const float*)d_in[2];   // separate buffers; launch per-matrix tiles.
    const float* Wv   = (const float*)d_in[3];
    const float* Wo   = (const float*)d_in[4];
    const float* wln1 = (const float*)d_in[5];
    const float* wln2 = (const float*)d_in[6];
    const float* Wg   = (const float*)d_in[7];
    const float* Wu   = (const float*)d_in[8];
    const float* Wd   = (const float*)d_in[9];
    const float* emb  = (const float*)d_in[11];
    const float* Wout = (const float*)d_in[12];
    const float* bout = (const float*)d_in[13];

    float* ws   = (float*)d_ws;
    float* buf  = ws + OFF_BUF;
    float* hT   = ws + OFF_HT;
    float* qb   = ws + OFF_Q;
    float* kcc  = ws + OFF_KC;
    float* vcc  = ws + OFF_VC;
    float* aoT  = ws + OFF_AOT;
    float* xp   = ws + OFF_XP;
    float* h2T  = ws + OFF_H2T;
    float* xoT  = ws + OFF_XOT;
    float* intT = ws + OFF_INT;
    float* part = ws + OFF_PART;

    // adaptive split counts: fit partial buffers in the remaining workspace
    size_t availF = (ws_size / 4 > OFF_PART) ? (ws_size / 4 - OFF_PART) : 0;
    auto fitS = [&](int smax, size_t rows) {
        int s = smax;
        while (s > 1 && (size_t)s * rows * TT > availF) s >>= 1;
        return s;
    };
    const int S_qkv = fitS(32, NQKV);
    const int S_wo  = fitS(32, D);
    const int S_gu  = fitS(8,  NGU);
    const int S_wd  = fitS(64, D);
    const int S_out = fitS(32, VOC);
    const int kc_qkv = D / S_qkv;
    const int kc_wo  = D / S_wo;
    const int kc_gu  = D / S_gu;
    const int kc_wd  = FF / S_wd;
    const int kc_out = D / S_out;

    k_init<<<512, 256, 0, stream>>>(x0, buf);
    for (int p = 0; p < GENN; ++p) {
        k_rmsnorm<<<32, 256, 0, stream>>>(buf + (size_t)p * D, SEQ * D, wln1, hT);
        // fused QKV: rows [0,4096)=Q, [4096,5120)=K, [5120,6144)=V
        // launched as three k_gemm calls writing into one fused partial layout
        // is not possible with disjoint W buffers -> launch per matrix but into
        // the fused partial at the right row offsets.
        k_gemm<<<64 * S_qkv / 4, 256, 0, stream>>>(hT, Wq, part, NQKV, D, 64, kc_qkv);
        k_gemm<<<16 * S_qkv / 4, 256, 0, stream>>>(hT, Wk, part + (size_t)4096 * TT, NQKV, D, 16, kc_qkv);
        k_gemm<<<16 * S_qkv / 4, 256, 0, stream>>>(hT, Wv, part + (size_t)5120 * TT, NQKV, D, 16, kc_qkv);
        k_qkv_finish<<<448, 256, 0, stream>>>(part, qb, kcc, vcc, p, S_qkv);
        k_attn<<<1024, 64, 0, stream>>>(qb, kcc, vcc, aoT, p);
        k_gemm<<<64 * S_wo / 4, 256, 0, stream>>>(aoT, Wo, part, D, D, 64, kc_wo);
        k_reduce_o<<<512, 256, 0, stream>>>(part, buf, xp, p, S_wo);
        k_rmsnorm<<<32, 256, 0, stream>>>(xp, D, wln2, h2T);
        // fused gate+up: rows [0,FF)=G, [FF,2FF)=U in one partial layout
        k_gemm<<<224 * S_gu / 4, 256, 0, stream>>>(h2T, Wg, part, NGU, D, 224, kc_gu);
        k_gemm<<<224 * S_gu / 4, 256, 0, stream>>>(h2T, Wu, part + (size_t)FF * TT, NGU, D, 224, kc_gu);
        k_silu_mul<<<1792, 256, 0, stream>>>(part, intT, S_gu);
        k_gemm<<<64 * S_wd / 4, 256, 0, stream>>>(intT, Wd, part, D, FF, 64, kc_wd);
        k_reduce_d<<<512, 256, 0, stream>>>(part, xp, xoT, S_wd);
        k_gemm<<<16 * S_out / 4, 256, 0, stream>>>(xoT, Wout, part, VOC, D, 16, kc_out);
        k_head<<<32, 256, 0, stream>>>(part, bout, emb, (int*)d_out, buf, p, S_out);
    }
}

// Round 3
// 10007.953 us; speedup vs baseline: 1.1239x; 1.1239x over previous
//
#include <hip/hip_runtime.h>

#define D 4096
#define NH 32
#define NKV 8
#define HD 128
#define FF 14336
#define VOC 1024
#define TT 32
#define GENN 8
#define SEQ 9
#define CK 16      // k-chunk per LDS stage

#define NQKV 6144   // fused QKV rows: 4096 Q + 1024 K + 1024 V
#define NGU  28672  // fused gate+up rows

// workspace offsets (floats)
#define OFF_BUF   0ull
#define OFF_HT    1179648ull
#define OFF_Q     1310720ull
#define OFF_KC    1441792ull
#define OFF_VC    1736704ull
#define OFF_AOT   2031616ull
#define OFF_XP    2162688ull
#define OFF_H2T   2293760ull
#define OFF_XOT   2424832ull
#define OFF_INT   2555904ull
#define OFF_PART  3014656ull

__global__ void k_init(const float* __restrict__ x0, float* __restrict__ buf) {
    int i = blockIdx.x * 256 + threadIdx.x;   // T*D threads
    int t = i / D, d = i % D;
    buf[(size_t)t * SEQ * D + d] = x0[i];
}

__global__ void k_rmsnorm(const float* __restrict__ base, int rowStride,
                          const float* __restrict__ w, float* __restrict__ outT) {
    int t = blockIdx.x;
    const float* x = base + (size_t)t * rowStride;
    float ss = 0.f;
    for (int d = threadIdx.x; d < D; d += 256) { float v = x[d]; ss += v * v; }
    #pragma unroll
    for (int m = 1; m < 64; m <<= 1) ss += __shfl_xor(ss, m);
    __shared__ float red[4];
    int wid = threadIdx.x >> 6;
    if ((threadIdx.x & 63) == 0) red[wid] = ss;
    __syncthreads();
    float tot = red[0] + red[1] + red[2] + red[3];
    float r = 1.0f / sqrtf(tot / (float)D + 1e-5f);
    for (int d = threadIdx.x; d < D; d += 256)
        outT[(size_t)d * TT + t] = x[d] * r * w[d];
}

// part[split][n][m] = sum_{k in split} X[m][k] * W[n][k]
// XT is [K][32]; all waves of a block share one k-split (blockIdx-derived)
// so XT reads are provably wave-uniform -> s_load broadcasts (SMEM pipe).
// W staged coalesced into wave-PRIVATE LDS tiles (64 rows x CK, pad 17),
// double-buffered, barrier-free. lane <-> output row.
__global__ __launch_bounds__(256) void k_gemm(const float* __restrict__ XT,
        const float* __restrict__ W, float* __restrict__ part,
        int N, int K, int ntilesB, int kc) {
    int wave = threadIdx.x >> 6;
    int lane = threadIdx.x & 63;
    int tb    = blockIdx.x % ntilesB;
    int split = blockIdx.x / ntilesB;
    int tile  = tb * 4 + wave;
    int k0    = split * kc;
    __shared__ float lds[4][2][64 * 17];
    float* mylds = &lds[wave][0][0];
    const int rr = lane >> 2;         // 0..15
    const int cc = (lane & 3) * 4;    // 0,4,8,12
    const float* wbase = W + (size_t)(tile * 64) * K + k0 + cc;
    float4 pf[4];
    float acc[32];
    #pragma unroll
    for (int m = 0; m < 32; ++m) acc[m] = 0.f;
    int nc = kc / CK;

    // stage chunk 0
    #pragma unroll
    for (int it = 0; it < 4; ++it)
        pf[it] = *(const float4*)(wbase + (size_t)(it * 16 + rr) * K);
    #pragma unroll
    for (int it = 0; it < 4; ++it)
        *(float4*)(mylds + (it * 16 + rr) * 17 + cc) = pf[it];

    const float* wr = mylds + lane * 17;
    for (int c = 0; c < nc; ++c) {
        if (c + 1 < nc) {
            const float* wc = wbase + (c + 1) * CK;
            #pragma unroll
            for (int it = 0; it < 4; ++it)
                pf[it] = *(const float4*)(wc + (size_t)(it * 16 + rr) * K);
        }
        const float* xc = XT + (size_t)(k0 + c * CK) * TT;   // wave-uniform
        const float* wb = wr + (c & 1) * (64 * 17);
        #pragma unroll
        for (int kk = 0; kk < CK; ++kk) {
            float wv = wb[kk];
            #pragma unroll
            for (int m = 0; m < 32; ++m)
                acc[m] = fmaf(xc[kk * TT + m], wv, acc[m]);
        }
        if (c + 1 < nc) {
            float* dstl = mylds + ((c + 1) & 1) * (64 * 17);
            #pragma unroll
            for (int it = 0; it < 4; ++it)
                *(float4*)(dstl + (it * 16 + rr) * 17 + cc) = pf[it];
        }
    }
    int n = tile * 64 + lane;
    float* dst = part + ((size_t)split * N + n) * TT;
    #pragma unroll
    for (int m = 0; m < 32; ++m) dst[m] = acc[m];
}

// reduce fused-QKV partials (S splits), apply RoPE at position p, fill caches
__global__ void k_qkv_finish(const float* __restrict__ pQKV, float* __restrict__ q,
                             float* __restrict__ kcache, float* __restrict__ vcache,
                             int p, int S) {
    int idx = blockIdx.x * 256 + threadIdx.x;
    float fp = (float)p;
    if (idx < TT * NH * 64) {            // Q rows [0, 4096)
        int d = idx & 63, h = (idx >> 6) & 31, t = idx >> 11;
        int n0 = h * HD + d, n1 = n0 + 64;
        float a = 0.f, b = 0.f;
        for (int s = 0; s < S; ++s) {
            a += pQKV[((size_t)s * NQKV + n0) * TT + t];
            b += pQKV[((size_t)s * NQKV + n1) * TT + t];
        }
        float ang = fp * powf(500000.0f, -(float)d * (1.0f / 64.0f));
        float cs = cosf(ang), sn = sinf(ang);
        q[(size_t)t * D + n0] = a * cs - b * sn;
        q[(size_t)t * D + n1] = b * cs + a * sn;
    } else if (idx < TT * NH * 64 + TT * NKV * 64) {   // K rows [4096, 5120)
        int r = idx - TT * NH * 64;
        int d = r & 63, kvh = (r >> 6) & 7, t = r >> 9;
        int n0 = 4096 + kvh * HD + d, n1 = n0 + 64;
        float a = 0.f, b = 0.f;
        for (int s = 0; s < S; ++s) {
            a += pQKV[((size_t)s * NQKV + n0) * TT + t];
            b += pQKV[((size_t)s * NQKV + n1) * TT + t];
        }
        float ang = fp * powf(500000.0f, -(float)d * (1.0f / 64.0f));
        float cs = cosf(ang), sn = sinf(ang);
        float* krow = kcache + (((size_t)t * SEQ + p) * NKV + kvh) * HD;
        krow[d] = a * cs - b * sn;
        krow[d + 64] = b * cs + a * sn;
    } else {                                            // V rows [5120, 6144)
        int r = idx - (TT * NH * 64 + TT * NKV * 64);
        int d = r & 127, kvh = (r >> 7) & 7, t = r >> 10;
        int n = 5120 + kvh * HD + d;
        float a = 0.f;
        for (int s = 0; s < S; ++s)
            a += pQKV[((size_t)s * NQKV + n) * TT + t];
        vcache[(((size_t)t * SEQ + p) * NKV + kvh) * HD + d] = a;
    }
}

__global__ __launch_bounds__(64) void k_attn(const float* __restrict__ q,
        const float* __restrict__ kcache, const float* __restrict__ vcache,
        float* __restrict__ aoT, int p) {
    int t = blockIdx.x >> 5;
    int h = blockIdx.x & 31;
    int kvh = h >> 2;                // G = NH/NKV = 4
    int lane = threadIdx.x;
    const float* qp = q + (size_t)t * D + h * HD;
    float q0 = qp[lane], q1 = qp[lane + 64];
    const float scale = 0.08838834764831845f;  // 1/sqrt(128)
    float s[SEQ];
    float mx = -1e30f;
    #pragma unroll
    for (int j = 0; j < SEQ; ++j) {
        const float* kr = kcache + (((size_t)t * SEQ + j) * NKV + kvh) * HD;
        float ps = q0 * kr[lane] + q1 * kr[lane + 64];
        #pragma unroll
        for (int m = 1; m < 64; m <<= 1) ps += __shfl_xor(ps, m);
        ps = (j <= p) ? ps * scale : -1e30f;
        s[j] = ps;
        mx = fmaxf(mx, ps);
    }
    float denom = 0.f;
    #pragma unroll
    for (int j = 0; j < SEQ; ++j) {
        float e = expf(s[j] - mx);
        e = (j <= p) ? e : 0.f;
        s[j] = e; denom += e;
    }
    float inv = 1.0f / denom;
    float o0 = 0.f, o1 = 0.f;
    #pragma unroll
    for (int j = 0; j < SEQ; ++j) {
        const float* vr = vcache + (((size_t)t * SEQ + j) * NKV + kvh) * HD;
        float w = s[j] * inv;
        o0 = fmaf(w, vr[lane], o0);
        o1 = fmaf(w, vr[lane + 64], o1);
    }
    aoT[(size_t)(h * HD + lane) * TT + t] = o0;
    aoT[(size_t)(h * HD + lane + 64) * TT + t] = o1;
}

__global__ void k_reduce_o(const float* __restrict__ part, const float* __restrict__ buf,
                           float* __restrict__ xp, int p, int S) {
    int idx = blockIdx.x * 256 + threadIdx.x;   // D*32
    int n = idx >> 5, t = idx & 31;
    float a = 0.f;
    for (int s = 0; s < S; ++s) a += part[(size_t)s * D * TT + idx];
    xp[(size_t)t * D + n] = a + buf[((size_t)t * SEQ + p) * D + n];
}

__global__ void k_silu_mul(const float* __restrict__ pGU, float* __restrict__ outT, int S) {
    int idx = blockIdx.x * 256 + threadIdx.x;   // FF*32, idx = n*32 + t
    float g = 0.f, u = 0.f;
    for (int s = 0; s < S; ++s) {
        g += pGU[(size_t)s * NGU * TT + idx];
        u += pGU[(size_t)s * NGU * TT + (size_t)FF * TT + idx];
    }
    float sg = g / (1.0f + expf(-g));
    outT[idx] = sg * u;
}

__global__ void k_reduce_d(const float* __restrict__ part, const float* __restrict__ xp,
                           float* __restrict__ xoT, int S) {
    int idx = blockIdx.x * 256 + threadIdx.x;   // D*32
    int n = idx >> 5, t = idx & 31;
    float a = 0.f;
    for (int s = 0; s < S; ++s) a += part[(size_t)s * D * TT + idx];
    xoT[idx] = a + xp[(size_t)t * D + n];
}

__global__ void k_head(const float* __restrict__ part, const float* __restrict__ bias,
                       const float* __restrict__ emb, int* __restrict__ toks,
                       float* __restrict__ buf, int p, int S) {
    int t = blockIdx.x;
    int tid = threadIdx.x;
    float bv = -1e30f; int bi = 0;
    for (int n = tid; n < VOC; n += 256) {
        float a = bias[n];
        for (int s = 0; s < S; ++s) a += part[((size_t)s * VOC + n) * TT + t];
        if (a > bv) { bv = a; bi = n; }   // ascending n -> first max kept
    }
    __shared__ float sv[256];
    __shared__ int si[256];
    sv[tid] = bv; si[tid] = bi;
    __syncthreads();
    for (int off = 128; off > 0; off >>= 1) {
        if (tid < off) {
            float v2 = sv[tid + off]; int i2 = si[tid + off];
            if (v2 > sv[tid] || (v2 == sv[tid] && i2 < si[tid])) { sv[tid] = v2; si[tid] = i2; }
        }
        __syncthreads();
    }
    int tok = si[0];
    if (tid == 0) toks[t * GENN + p] = tok;
    const float* er = emb + (size_t)tok * D;
    float* brow = buf + ((size_t)t * SEQ + (p + 1)) * D;
    for (int d = tid; d < D; d += 256) brow[d] = er[d];
}

extern "C" void kernel_launch(void* const* d_in, const int* in_sizes, int n_in,
                              void* d_out, int out_size, void* d_ws, size_t ws_size,
                              hipStream_t stream) {
    const float* x0   = (const float*)d_in[0];
    const float* Wq   = (const float*)d_in[1];
    const float* Wk   = (const float*)d_in[2];
    const float* Wv   = (const float*)d_in[3];
    const float* Wo   = (const float*)d_in[4];
    const float* wln1 = (const float*)d_in[5];
    const float* wln2 = (const float*)d_in[6];
    const float* Wg   = (const float*)d_in[7];
    const float* Wu   = (const float*)d_in[8];
    const float* Wd   = (const float*)d_in[9];
    const float* emb  = (const float*)d_in[11];
    const float* Wout = (const float*)d_in[12];
    const float* bout = (const float*)d_in[13];

    float* ws   = (float*)d_ws;
    float* buf  = ws + OFF_BUF;
    float* hT   = ws + OFF_HT;
    float* qb   = ws + OFF_Q;
    float* kcc  = ws + OFF_KC;
    float* vcc  = ws + OFF_VC;
    float* aoT  = ws + OFF_AOT;
    float* xp   = ws + OFF_XP;
    float* h2T  = ws + OFF_H2T;
    float* xoT  = ws + OFF_XOT;
    float* intT = ws + OFF_INT;
    float* part = ws + OFF_PART;

    // adaptive split counts: fit partial buffers in the remaining workspace
    size_t availF = (ws_size / 4 > OFF_PART) ? (ws_size / 4 - OFF_PART) : 0;
    auto fitS = [&](int smax, size_t rows) {
        int s = smax;
        while (s > 1 && (size_t)s * rows * TT > availF) s >>= 1;
        return s;
    };
    const int S_qkv = fitS(32, NQKV);
    const int S_wo  = fitS(32, D);
    const int S_gu  = fitS(16, NGU);
    const int S_wd  = fitS(64, D);
    const int S_out = fitS(16, VOC);
    const int kc_qkv = D / S_qkv;
    const int kc_wo  = D / S_wo;
    const int kc_gu  = D / S_gu;
    const int kc_wd  = FF / S_wd;
    const int kc_out = D / S_out;

    k_init<<<512, 256, 0, stream>>>(x0, buf);
    for (int p = 0; p < GENN; ++p) {
        k_rmsnorm<<<32, 256, 0, stream>>>(buf + (size_t)p * D, SEQ * D, wln1, hT);
        // fused QKV partial layout: rows [0,4096)=Q, [4096,5120)=K, [5120,6144)=V
        k_gemm<<<16 * S_qkv, 256, 0, stream>>>(hT, Wq, part, NQKV, D, 16, kc_qkv);
        k_gemm<<< 4 * S_qkv, 256, 0, stream>>>(hT, Wk, part + (size_t)4096 * TT, NQKV, D, 4, kc_qkv);
        k_gemm<<< 4 * S_qkv, 256, 0, stream>>>(hT, Wv, part + (size_t)5120 * TT, NQKV, D, 4, kc_qkv);
        k_qkv_finish<<<448, 256, 0, stream>>>(part, qb, kcc, vcc, p, S_qkv);
        k_attn<<<1024, 64, 0, stream>>>(qb, kcc, vcc, aoT, p);
        k_gemm<<<16 * S_wo, 256, 0, stream>>>(aoT, Wo, part, D, D, 16, kc_wo);
        k_reduce_o<<<512, 256, 0, stream>>>(part, buf, xp, p, S_wo);
        k_rmsnorm<<<32, 256, 0, stream>>>(xp, D, wln2, h2T);
        // fused gate+up partial layout: rows [0,FF)=G, [FF,2FF)=U
        k_gemm<<<56 * S_gu, 256, 0, stream>>>(h2T, Wg, part, NGU, D, 56, kc_gu);
        k_gemm<<<56 * S_gu, 256, 0, stream>>>(h2T, Wu, part + (size_t)FF * TT, NGU, D, 56, kc_gu);
        k_silu_mul<<<1792, 256, 0, stream>>>(part, intT, S_gu);
        k_gemm<<<16 * S_wd, 256, 0, stream>>>(intT, Wd, part, D, FF, 16, kc_wd);
        k_reduce_d<<<512, 256, 0, stream>>>(part, xp, xoT, S_wd);
        k_gemm<<< 4 * S_out, 256, 0, stream>>>(xoT, Wout, part, VOC, D, 4, kc_out);
        k_head<<<32, 256, 0, stream>>>(part, bout, emb, (int*)d_out, buf, p, S_out);
    }
}

// Round 4
// 6203.512 us; speedup vs baseline: 1.8132x; 1.6133x over previous
//
#include <hip/hip_runtime.h>

#define D 4096
#define NH 32
#define NKV 8
#define HD 128
#define FF 14336
#define VOC 1024
#define TT 32
#define GENN 8
#define SEQ 9
#define CK 16      // k-chunk per prefetch stage

#define NQKV 6144   // fused QKV rows: 4096 Q + 1024 K + 1024 V
#define NGU  28672  // fused gate+up rows

// workspace offsets (floats)
#define OFF_BUF   0ull
#define OFF_HT    1179648ull
#define OFF_Q     1310720ull
#define OFF_KC    1441792ull
#define OFF_VC    1736704ull
#define OFF_AOT   2031616ull
#define OFF_XP    2162688ull
#define OFF_H2T   2293760ull
#define OFF_XOT   2424832ull
#define OFF_INT   2555904ull
#define OFF_PART  3014656ull

__global__ void k_init(const float* __restrict__ x0, float* __restrict__ buf) {
    int i = blockIdx.x * 256 + threadIdx.x;   // T*D threads
    int t = i / D, d = i % D;
    buf[(size_t)t * SEQ * D + d] = x0[i];
}

__global__ void k_rmsnorm(const float* __restrict__ base, int rowStride,
                          const float* __restrict__ w, float* __restrict__ outT) {
    int t = blockIdx.x;
    const float* x = base + (size_t)t * rowStride;
    float ss = 0.f;
    for (int d = threadIdx.x; d < D; d += 256) { float v = x[d]; ss += v * v; }
    #pragma unroll
    for (int m = 1; m < 64; m <<= 1) ss += __shfl_xor(ss, m);
    __shared__ float red[4];
    int wid = threadIdx.x >> 6;
    if ((threadIdx.x & 63) == 0) red[wid] = ss;
    __syncthreads();
    float tot = red[0] + red[1] + red[2] + red[3];
    float r = 1.0f / sqrtf(tot / (float)D + 1e-5f);
    for (int d = threadIdx.x; d < D; d += 256)
        outT[(size_t)d * TT + t] = x[d] * r * w[d];
}

// part[split][m][n] = sum_{k in split} X[m][k] * W[n-rowOff][k]   (coalesced stores)
// XT is [K][32]; split is blockIdx-derived -> X addresses wave-uniform -> s_load.
// No LDS: lane <-> W row, float4 stream with 2-chunk register double buffer.
// lgkmcnt carries only SMEM (X), vmcnt only W stream -> independent pipelines.
__global__ __launch_bounds__(256, 2) void k_gemm(const float* __restrict__ XT,
        const float* __restrict__ W, float* __restrict__ part,
        int N, int K, int ntilesB, int kc, int rowOff) {
    int wave = threadIdx.x >> 6;
    int lane = threadIdx.x & 63;
    int tb    = blockIdx.x % ntilesB;
    int split = blockIdx.x / ntilesB;
    int tile  = tb * 4 + wave;
    int k0    = split * kc;
    const float* wrow = W + (size_t)(tile * 64 + lane) * K + k0;
    const float* xb = XT + (size_t)k0 * TT;
    float acc[32];
    #pragma unroll
    for (int m = 0; m < 32; ++m) acc[m] = 0.f;
    int nc = kc / CK;   // always even here
    float4 pa[4], pb[4];
    #pragma unroll
    for (int j = 0; j < 4; ++j) pa[j] = *(const float4*)(wrow + j * 4);
    for (int c = 0; c < nc; c += 2) {
        {   // issue loads for chunk c+1
            const float* w1 = wrow + (size_t)(c + 1) * CK;
            #pragma unroll
            for (int j = 0; j < 4; ++j) pb[j] = *(const float4*)(w1 + j * 4);
        }
        {   // compute chunk c from pa
            const float* x0 = xb + (size_t)c * CK * TT;
            #pragma unroll
            for (int j = 0; j < 4; ++j) {
                #pragma unroll
                for (int q = 0; q < 4; ++q) {
                    float wv = q == 0 ? pa[j].x : q == 1 ? pa[j].y : q == 2 ? pa[j].z : pa[j].w;
                    const float* xk = x0 + (j * 4 + q) * TT;
                    #pragma unroll
                    for (int m = 0; m < 32; ++m) acc[m] = fmaf(xk[m], wv, acc[m]);
                }
            }
        }
        if (c + 2 < nc) {   // issue loads for chunk c+2
            const float* w2 = wrow + (size_t)(c + 2) * CK;
            #pragma unroll
            for (int j = 0; j < 4; ++j) pa[j] = *(const float4*)(w2 + j * 4);
        }
        {   // compute chunk c+1 from pb
            const float* x1 = xb + (size_t)(c + 1) * CK * TT;
            #pragma unroll
            for (int j = 0; j < 4; ++j) {
                #pragma unroll
                for (int q = 0; q < 4; ++q) {
                    float wv = q == 0 ? pb[j].x : q == 1 ? pb[j].y : q == 2 ? pb[j].z : pb[j].w;
                    const float* xk = x1 + (j * 4 + q) * TT;
                    #pragma unroll
                    for (int m = 0; m < 32; ++m) acc[m] = fmaf(xk[m], wv, acc[m]);
                }
            }
        }
    }
    float* dst = part + (size_t)split * TT * N + (size_t)rowOff + (size_t)tile * 64 + lane;
    #pragma unroll
    for (int m = 0; m < 32; ++m) dst[(size_t)m * N] = acc[m];
}

// reduce fused-QKV partials (layout [s][t][NQKV]), RoPE at position p, fill caches
__global__ void k_qkv_finish(const float* __restrict__ pQKV, float* __restrict__ q,
                             float* __restrict__ kcache, float* __restrict__ vcache,
                             int p, int S) {
    int idx = blockIdx.x * 256 + threadIdx.x;
    float fp = (float)p;
    if (idx < TT * NH * 64) {            // Q rows [0, 4096)
        int d = idx & 63, h = (idx >> 6) & 31, t = idx >> 11;
        int n0 = h * HD + d, n1 = n0 + 64;
        float a = 0.f, b = 0.f;
        for (int s = 0; s < S; ++s) {
            const float* row = pQKV + ((size_t)s * TT + t) * NQKV;
            a += row[n0];
            b += row[n1];
        }
        float ang = fp * powf(500000.0f, -(float)d * (1.0f / 64.0f));
        float cs = cosf(ang), sn = sinf(ang);
        q[(size_t)t * D + n0] = a * cs - b * sn;
        q[(size_t)t * D + n1] = b * cs + a * sn;
    } else if (idx < TT * NH * 64 + TT * NKV * 64) {   // K rows [4096, 5120)
        int r = idx - TT * NH * 64;
        int d = r & 63, kvh = (r >> 6) & 7, t = r >> 9;
        int n0 = 4096 + kvh * HD + d, n1 = n0 + 64;
        float a = 0.f, b = 0.f;
        for (int s = 0; s < S; ++s) {
            const float* row = pQKV + ((size_t)s * TT + t) * NQKV;
            a += row[n0];
            b += row[n1];
        }
        float ang = fp * powf(500000.0f, -(float)d * (1.0f / 64.0f));
        float cs = cosf(ang), sn = sinf(ang);
        float* krow = kcache + (((size_t)t * SEQ + p) * NKV + kvh) * HD;
        krow[d] = a * cs - b * sn;
        krow[d + 64] = b * cs + a * sn;
    } else {                                            // V rows [5120, 6144)
        int r = idx - (TT * NH * 64 + TT * NKV * 64);
        int d = r & 127, kvh = (r >> 7) & 7, t = r >> 10;
        int n = 5120 + kvh * HD + d;
        float a = 0.f;
        for (int s = 0; s < S; ++s)
            a += pQKV[((size_t)s * TT + t) * NQKV + n];
        vcache[(((size_t)t * SEQ + p) * NKV + kvh) * HD + d] = a;
    }
}

__global__ __launch_bounds__(64) void k_attn(const float* __restrict__ q,
        const float* __restrict__ kcache, const float* __restrict__ vcache,
        float* __restrict__ aoT, int p) {
    int t = blockIdx.x >> 5;
    int h = blockIdx.x & 31;
    int kvh = h >> 2;                // G = NH/NKV = 4
    int lane = threadIdx.x;
    const float* qp = q + (size_t)t * D + h * HD;
    float q0 = qp[lane], q1 = qp[lane + 64];
    const float scale = 0.08838834764831845f;  // 1/sqrt(128)
    float s[SEQ];
    float mx = -1e30f;
    #pragma unroll
    for (int j = 0; j < SEQ; ++j) {
        const float* kr = kcache + (((size_t)t * SEQ + j) * NKV + kvh) * HD;
        float ps = q0 * kr[lane] + q1 * kr[lane + 64];
        #pragma unroll
        for (int m = 1; m < 64; m <<= 1) ps += __shfl_xor(ps, m);
        ps = (j <= p) ? ps * scale : -1e30f;
        s[j] = ps;
        mx = fmaxf(mx, ps);
    }
    float denom = 0.f;
    #pragma unroll
    for (int j = 0; j < SEQ; ++j) {
        float e = expf(s[j] - mx);
        e = (j <= p) ? e : 0.f;
        s[j] = e; denom += e;
    }
    float inv = 1.0f / denom;
    float o0 = 0.f, o1 = 0.f;
    #pragma unroll
    for (int j = 0; j < SEQ; ++j) {
        const float* vr = vcache + (((size_t)t * SEQ + j) * NKV + kvh) * HD;
        float w = s[j] * inv;
        o0 = fmaf(w, vr[lane], o0);
        o1 = fmaf(w, vr[lane + 64], o1);
    }
    aoT[(size_t)(h * HD + lane) * TT + t] = o0;
    aoT[(size_t)(h * HD + lane + 64) * TT + t] = o1;
}

// part layout [s][t][D]; grid (16, 32); fully coalesced reads
__global__ void k_reduce_o(const float* __restrict__ part, const float* __restrict__ buf,
                           float* __restrict__ xp, int p, int S) {
    int n = blockIdx.x * 256 + threadIdx.x;
    int t = blockIdx.y;
    float a = 0.f;
    for (int s = 0; s < S; ++s) a += part[((size_t)s * TT + t) * D + n];
    xp[(size_t)t * D + n] = a + buf[((size_t)t * SEQ + p) * D + n];
}

// part layout [s][t][NGU]; grid (56, 32); writes intT[n][t]
__global__ void k_silu_mul(const float* __restrict__ pGU, float* __restrict__ outT, int S) {
    int n = blockIdx.x * 256 + threadIdx.x;
    int t = blockIdx.y;
    float g = 0.f, u = 0.f;
    for (int s = 0; s < S; ++s) {
        const float* row = pGU + ((size_t)s * TT + t) * NGU;
        g += row[n];
        u += row[n + FF];
    }
    float sg = g / (1.0f + expf(-g));
    outT[(size_t)n * TT + t] = sg * u;
}

// part layout [s][t][D]; grid (16, 32); writes xoT[n][t]
__global__ void k_reduce_d(const float* __restrict__ part, const float* __restrict__ xp,
                           float* __restrict__ xoT, int S) {
    int n = blockIdx.x * 256 + threadIdx.x;
    int t = blockIdx.y;
    float a = 0.f;
    for (int s = 0; s < S; ++s) a += part[((size_t)s * TT + t) * D + n];
    xoT[(size_t)n * TT + t] = a + xp[(size_t)t * D + n];
}

// part layout [s][t][VOC]
__global__ void k_head(const float* __restrict__ part, const float* __restrict__ bias,
                       const float* __restrict__ emb, int* __restrict__ toks,
                       float* __restrict__ buf, int p, int S) {
    int t = blockIdx.x;
    int tid = threadIdx.x;
    float bv = -1e30f; int bi = 0;
    for (int n = tid; n < VOC; n += 256) {
        float a = bias[n];
        for (int s = 0; s < S; ++s) a += part[((size_t)s * TT + t) * VOC + n];
        if (a > bv) { bv = a; bi = n; }   // ascending n -> first max kept
    }
    __shared__ float sv[256];
    __shared__ int si[256];
    sv[tid] = bv; si[tid] = bi;
    __syncthreads();
    for (int off = 128; off > 0; off >>= 1) {
        if (tid < off) {
            float v2 = sv[tid + off]; int i2 = si[tid + off];
            if (v2 > sv[tid] || (v2 == sv[tid] && i2 < si[tid])) { sv[tid] = v2; si[tid] = i2; }
        }
        __syncthreads();
    }
    int tok = si[0];
    if (tid == 0) toks[t * GENN + p] = tok;
    const float* er = emb + (size_t)tok * D;
    float* brow = buf + ((size_t)t * SEQ + (p + 1)) * D;
    for (int d = tid; d < D; d += 256) brow[d] = er[d];
}

extern "C" void kernel_launch(void* const* d_in, const int* in_sizes, int n_in,
                              void* d_out, int out_size, void* d_ws, size_t ws_size,
                              hipStream_t stream) {
    const float* x0   = (const float*)d_in[0];
    const float* Wq   = (const float*)d_in[1];
    const float* Wk   = (const float*)d_in[2];
    const float* Wv   = (const float*)d_in[3];
    const float* Wo   = (const float*)d_in[4];
    const float* wln1 = (const float*)d_in[5];
    const float* wln2 = (const float*)d_in[6];
    const float* Wg   = (const float*)d_in[7];
    const float* Wu   = (const float*)d_in[8];
    const float* Wd   = (const float*)d_in[9];
    const float* emb  = (const float*)d_in[11];
    const float* Wout = (const float*)d_in[12];
    const float* bout = (const float*)d_in[13];

    float* ws   = (float*)d_ws;
    float* buf  = ws + OFF_BUF;
    float* hT   = ws + OFF_HT;
    float* qb   = ws + OFF_Q;
    float* kcc  = ws + OFF_KC;
    float* vcc  = ws + OFF_VC;
    float* aoT  = ws + OFF_AOT;
    float* xp   = ws + OFF_XP;
    float* h2T  = ws + OFF_H2T;
    float* xoT  = ws + OFF_XOT;
    float* intT = ws + OFF_INT;
    float* part = ws + OFF_PART;

    // adaptive split counts: fit partial buffers in the remaining workspace
    size_t availF = (ws_size / 4 > OFF_PART) ? (ws_size / 4 - OFF_PART) : 0;
    auto fitS = [&](int smax, size_t rows) {
        int s = smax;
        while (s > 1 && (size_t)s * rows * TT > availF) s >>= 1;
        return s;
    };
    const int S_qkv = fitS(32, NQKV);
    const int S_wo  = fitS(32, D);
    const int S_gu  = fitS(16, NGU);
    const int S_wd  = fitS(64, D);
    const int S_out = fitS(64, VOC);
    const int kc_qkv = D / S_qkv;
    const int kc_wo  = D / S_wo;
    const int kc_gu  = D / S_gu;
    const int kc_wd  = FF / S_wd;
    const int kc_out = D / S_out;

    k_init<<<512, 256, 0, stream>>>(x0, buf);
    for (int p = 0; p < GENN; ++p) {
        k_rmsnorm<<<32, 256, 0, stream>>>(buf + (size_t)p * D, SEQ * D, wln1, hT);
        // fused QKV partial layout [s][t][NQKV]: cols [0,4096)=Q, [4096,5120)=K, [5120,6144)=V
        k_gemm<<<16 * S_qkv, 256, 0, stream>>>(hT, Wq, part, NQKV, D, 16, kc_qkv, 0);
        k_gemm<<< 4 * S_qkv, 256, 0, stream>>>(hT, Wk, part, NQKV, D, 4, kc_qkv, 4096);
        k_gemm<<< 4 * S_qkv, 256, 0, stream>>>(hT, Wv, part, NQKV, D, 4, kc_qkv, 5120);
        k_qkv_finish<<<448, 256, 0, stream>>>(part, qb, kcc, vcc, p, S_qkv);
        k_attn<<<1024, 64, 0, stream>>>(qb, kcc, vcc, aoT, p);
        k_gemm<<<16 * S_wo, 256, 0, stream>>>(aoT, Wo, part, D, D, 16, kc_wo, 0);
        k_reduce_o<<<dim3(16, 32), 256, 0, stream>>>(part, buf, xp, p, S_wo);
        k_rmsnorm<<<32, 256, 0, stream>>>(xp, D, wln2, h2T);
        // fused gate+up partial layout [s][t][NGU]: cols [0,FF)=G, [FF,2FF)=U
        k_gemm<<<56 * S_gu, 256, 0, stream>>>(h2T, Wg, part, NGU, D, 56, kc_gu, 0);
        k_gemm<<<56 * S_gu, 256, 0, stream>>>(h2T, Wu, part, NGU, D, 56, kc_gu, FF);
        k_silu_mul<<<dim3(56, 32), 256, 0, stream>>>(part, intT, S_gu);
        k_gemm<<<16 * S_wd, 256, 0, stream>>>(intT, Wd, part, D, FF, 16, kc_wd, 0);
        k_reduce_d<<<dim3(16, 32), 256, 0, stream>>>(part, xp, xoT, S_wd);
        k_gemm<<< 4 * S_out, 256, 0, stream>>>(xoT, Wout, part, VOC, D, 4, kc_out, 0);
        k_head<<<32, 256, 0, stream>>>(part, bout, emb, (int*)d_out, buf, p, S_out);
    }
}

// Round 5
// 3066.404 us; speedup vs baseline: 3.6682x; 2.0231x over previous
//
#include <hip/hip_runtime.h>
#include <hip/hip_bf16.h>

#define D 4096
#define NH 32
#define NKV 8
#define HD 128
#define FF 14336
#define VOC 1024
#define TT 32
#define GENN 8
#define SEQ 9

#define NQKV 6144   // fused QKV cols: 4096 Q + 1024 K + 1024 V
#define NGU  28672  // fused gate+up cols

// workspace offsets (floats)
#define OFF_BUF   0ull
#define OFF_HT    1179648ull
#define OFF_Q     1310720ull
#define OFF_KC    1441792ull
#define OFF_VC    1736704ull
#define OFF_AOT   2031616ull
#define OFF_XP    2162688ull
#define OFF_H2T   2293760ull
#define OFF_XOT   2424832ull
#define OFF_INT   2555904ull
#define OFF_XPK   3014656ull   // packed X fragments: up to FF/16*512 dwords = 458752
#define OFF_PART  3473408ull

typedef __attribute__((ext_vector_type(8))) short short8;
typedef __attribute__((ext_vector_type(16))) float f32x16;

__device__ inline void cvt_hi_lo(const float* x, short8& hi, short8& lo) {
    union U { unsigned u[4]; short8 s; };
    U H, L;
    #pragma unroll
    for (int j = 0; j < 4; ++j) {
        float2 p = make_float2(x[2 * j], x[2 * j + 1]);
        __hip_bfloat162 h = __float22bfloat162_rn(p);
        unsigned hb; __builtin_memcpy(&hb, &h, 4);
        H.u[j] = hb;
        float f0 = __uint_as_float(hb << 16);
        float f1 = __uint_as_float(hb & 0xffff0000u);
        __hip_bfloat162 l = __float22bfloat162_rn(make_float2(p.x - f0, p.y - f1));
        unsigned lb; __builtin_memcpy(&lb, &l, 4);
        L.u[j] = lb;
    }
    hi = H.s; lo = L.s;
}

__global__ void k_init(const float* __restrict__ x0, float* __restrict__ buf) {
    int i = blockIdx.x * 256 + threadIdx.x;   // T*D threads
    int t = i / D, d = i % D;
    buf[(size_t)t * SEQ * D + d] = x0[i];
}

__global__ void k_rmsnorm(const float* __restrict__ base, int rowStride,
                          const float* __restrict__ w, float* __restrict__ outT) {
    int t = blockIdx.x;
    const float* x = base + (size_t)t * rowStride;
    float ss = 0.f;
    for (int d = threadIdx.x; d < D; d += 256) { float v = x[d]; ss += v * v; }
    #pragma unroll
    for (int m = 1; m < 64; m <<= 1) ss += __shfl_xor(ss, m);
    __shared__ float red[4];
    int wid = threadIdx.x >> 6;
    if ((threadIdx.x & 63) == 0) red[wid] = ss;
    __syncthreads();
    float tot = red[0] + red[1] + red[2] + red[3];
    float r = 1.0f / sqrtf(tot / (float)D + 1e-5f);
    for (int d = threadIdx.x; d < D; d += 256)
        outT[(size_t)d * TT + t] = x[d] * r * w[d];
}

// pack XT [K][32] fp32 into MFMA B fragments, bf16 hi/lo:
// Xp[frag][2][64][4] dwords; lane=((k&8)<<2)|m, e=k&7, element e -> dword e/2 (low=even)
__global__ __launch_bounds__(256) void k_pack(const float* __restrict__ XT,
                                              unsigned* __restrict__ Xp) {
    int frag = blockIdx.x * 4 + (threadIdx.x >> 6);
    int lane = threadIdx.x & 63;
    int m = lane & 31, half = lane >> 5;
    const float* src = XT + (size_t)(frag * 16 + half * 8) * TT + m;
    float x[8];
    #pragma unroll
    for (int e = 0; e < 8; ++e) x[e] = src[e * TT];
    short8 hi, lo;
    cvt_hi_lo(x, hi, lo);
    unsigned* dst = Xp + (size_t)frag * 512 + lane * 4;
    union U { short8 s; uint4 u; };
    U uh, ul; uh.s = hi; ul.s = lo;
    *(uint4*)dst = uh.u;
    *(uint4*)(dst + 256) = ul.u;
}

// part[s][n][m] += over split k-range of X[m][k]*W[n][k], via bf16x3 MFMA.
// Per wave: 32 W-rows x 32 tokens. A = W (on-the-fly bf16 hi/lo), B = packed X.
__global__ __launch_bounds__(256, 4) void k_gemm_mfma(
        const unsigned* __restrict__ Xp, const float* __restrict__ W,
        float* __restrict__ part, int Nfull, int K, int ntiles, int kc, int rowOff) {
    int wave = threadIdx.x >> 6, lane = threadIdx.x & 63;
    int unit = blockIdx.x * 4 + wave;
    int tile = unit % ntiles, split = unit / ntiles;
    int k0 = split * kc;
    int m = lane & 31, half = lane >> 5;
    const float* wptr = W + (size_t)(tile * 32 + m) * K + k0 + half * 8;
    const unsigned* xptr = Xp + (size_t)(k0 >> 4) * 512 + lane * 4;
    f32x16 acc;
    #pragma unroll
    for (int i = 0; i < 16; ++i) acc[i] = 0.f;
    int steps = kc >> 4;
    float4 wa0 = *(const float4*)wptr;
    float4 wa1 = *(const float4*)(wptr + 4);
    uint4 xa_h = *(const uint4*)xptr;
    uint4 xa_l = *(const uint4*)(xptr + 256);
    for (int c = 0; c < steps; ++c) {
        int cn = (c + 1 < steps) ? c + 1 : c;
        const float* wn = wptr + (size_t)cn * 16;
        float4 wb0 = *(const float4*)wn;
        float4 wb1 = *(const float4*)(wn + 4);
        const unsigned* xn = xptr + (size_t)cn * 512;
        uint4 xb_h = *(const uint4*)xn;
        uint4 xb_l = *(const uint4*)(xn + 256);

        float xv[8] = {wa0.x, wa0.y, wa0.z, wa0.w, wa1.x, wa1.y, wa1.z, wa1.w};
        short8 whi, wlo;
        cvt_hi_lo(xv, whi, wlo);
        union U { uint4 u; short8 s; };
        U bh, bl; bh.u = xa_h; bl.u = xa_l;
        acc = __builtin_amdgcn_mfma_f32_32x32x16_bf16(whi, bh.s, acc, 0, 0, 0);
        acc = __builtin_amdgcn_mfma_f32_32x32x16_bf16(whi, bl.s, acc, 0, 0, 0);
        acc = __builtin_amdgcn_mfma_f32_32x32x16_bf16(wlo, bh.s, acc, 0, 0, 0);
        wa0 = wb0; wa1 = wb1; xa_h = xb_h; xa_l = xb_l;
    }
    int n0 = rowOff + tile * 32;
    float* dst = part + (size_t)split * Nfull * TT + (size_t)n0 * TT + m;
    #pragma unroll
    for (int r = 0; r < 16; ++r) {
        int rr = (r & 3) + 8 * (r >> 2) + 4 * half;
        dst[(size_t)rr * TT] = acc[r];
    }
}

// reduce fused-QKV partials (layout [s][n][TT]), RoPE at position p, fill caches
__global__ void k_qkv_finish(const float* __restrict__ pQKV, float* __restrict__ q,
                             float* __restrict__ kcache, float* __restrict__ vcache,
                             int p, int S) {
    int idx = blockIdx.x * 256 + threadIdx.x;
    float fp = (float)p;
    if (idx < TT * NH * 64) {            // Q cols [0, 4096)
        int d = idx & 63, h = (idx >> 6) & 31, t = idx >> 11;
        int n0 = h * HD + d, n1 = n0 + 64;
        float a = 0.f, b = 0.f;
        for (int s = 0; s < S; ++s) {
            a += pQKV[((size_t)s * NQKV + n0) * TT + t];
            b += pQKV[((size_t)s * NQKV + n1) * TT + t];
        }
        float ang = fp * powf(500000.0f, -(float)d * (1.0f / 64.0f));
        float cs = cosf(ang), sn = sinf(ang);
        q[(size_t)t * D + n0] = a * cs - b * sn;
        q[(size_t)t * D + n1] = b * cs + a * sn;
    } else if (idx < TT * NH * 64 + TT * NKV * 64) {   // K cols [4096, 5120)
        int r = idx - TT * NH * 64;
        int d = r & 63, kvh = (r >> 6) & 7, t = r >> 9;
        int n0 = 4096 + kvh * HD + d, n1 = n0 + 64;
        float a = 0.f, b = 0.f;
        for (int s = 0; s < S; ++s) {
            a += pQKV[((size_t)s * NQKV + n0) * TT + t];
            b += pQKV[((size_t)s * NQKV + n1) * TT + t];
        }
        float ang = fp * powf(500000.0f, -(float)d * (1.0f / 64.0f));
        float cs = cosf(ang), sn = sinf(ang);
        float* krow = kcache + (((size_t)t * SEQ + p) * NKV + kvh) * HD;
        krow[d] = a * cs - b * sn;
        krow[d + 64] = b * cs + a * sn;
    } else {                                            // V cols [5120, 6144)
        int r = idx - (TT * NH * 64 + TT * NKV * 64);
        int d = r & 127, kvh = (r >> 7) & 7, t = r >> 10;
        int n = 5120 + kvh * HD + d;
        float a = 0.f;
        for (int s = 0; s < S; ++s)
            a += pQKV[((size_t)s * NQKV + n) * TT + t];
        vcache[(((size_t)t * SEQ + p) * NKV + kvh) * HD + d] = a;
    }
}

__global__ __launch_bounds__(64) void k_attn(const float* __restrict__ q,
        const float* __restrict__ kcache, const float* __restrict__ vcache,
        float* __restrict__ aoT, int p) {
    int t = blockIdx.x >> 5;
    int h = blockIdx.x & 31;
    int kvh = h >> 2;                // G = NH/NKV = 4
    int lane = threadIdx.x;
    const float* qp = q + (size_t)t * D + h * HD;
    float q0 = qp[lane], q1 = qp[lane + 64];
    const float scale = 0.08838834764831845f;  // 1/sqrt(128)
    float s[SEQ];
    float mx = -1e30f;
    #pragma unroll
    for (int j = 0; j < SEQ; ++j) {
        const float* kr = kcache + (((size_t)t * SEQ + j) * NKV + kvh) * HD;
        float ps = q0 * kr[lane] + q1 * kr[lane + 64];
        #pragma unroll
        for (int mm = 1; mm < 64; mm <<= 1) ps += __shfl_xor(ps, mm);
        ps = (j <= p) ? ps * scale : -1e30f;
        s[j] = ps;
        mx = fmaxf(mx, ps);
    }
    float denom = 0.f;
    #pragma unroll
    for (int j = 0; j < SEQ; ++j) {
        float e = expf(s[j] - mx);
        e = (j <= p) ? e : 0.f;
        s[j] = e; denom += e;
    }
    float inv = 1.0f / denom;
    float o0 = 0.f, o1 = 0.f;
    #pragma unroll
    for (int j = 0; j < SEQ; ++j) {
        const float* vr = vcache + (((size_t)t * SEQ + j) * NKV + kvh) * HD;
        float w = s[j] * inv;
        o0 = fmaf(w, vr[lane], o0);
        o1 = fmaf(w, vr[lane + 64], o1);
    }
    aoT[(size_t)(h * HD + lane) * TT + t] = o0;
    aoT[(size_t)(h * HD + lane + 64) * TT + t] = o1;
}

// part layout [s][n][TT]
__global__ void k_reduce_o(const float* __restrict__ part, const float* __restrict__ buf,
                           float* __restrict__ xp, int p, int S) {
    int idx = blockIdx.x * 256 + threadIdx.x;   // D*32
    int n = idx >> 5, t = idx & 31;
    float a = 0.f;
    for (int s = 0; s < S; ++s) a += part[(size_t)s * D * TT + idx];
    xp[(size_t)t * D + n] = a + buf[((size_t)t * SEQ + p) * D + n];
}

__global__ void k_silu_mul(const float* __restrict__ pGU, float* __restrict__ outT, int S) {
    int idx = blockIdx.x * 256 + threadIdx.x;   // FF*32, idx = n*32 + t
    float g = 0.f, u = 0.f;
    for (int s = 0; s < S; ++s) {
        g += pGU[(size_t)s * NGU * TT + idx];
        u += pGU[(size_t)s * NGU * TT + (size_t)FF * TT + idx];
    }
    float sg = g / (1.0f + expf(-g));
    outT[idx] = sg * u;
}

__global__ void k_reduce_d(const float* __restrict__ part, const float* __restrict__ xp,
                           float* __restrict__ xoT, int S) {
    int idx = blockIdx.x * 256 + threadIdx.x;   // D*32
    int n = idx >> 5, t = idx & 31;
    float a = 0.f;
    for (int s = 0; s < S; ++s) a += part[(size_t)s * D * TT + idx];
    xoT[idx] = a + xp[(size_t)t * D + n];
}

// part layout [s][n][TT]
__global__ void k_head(const float* __restrict__ part, const float* __restrict__ bias,
                       const float* __restrict__ emb, int* __restrict__ toks,
                       float* __restrict__ buf, int p, int S) {
    int t = blockIdx.x;
    int tid = threadIdx.x;
    float bv = -1e30f; int bi = 0;
    for (int n = tid; n < VOC; n += 256) {
        float a = bias[n];
        for (int s = 0; s < S; ++s) a += part[((size_t)s * VOC + n) * TT + t];
        if (a > bv) { bv = a; bi = n; }   // ascending n -> first max kept
    }
    __shared__ float sv[256];
    __shared__ int si[256];
    sv[tid] = bv; si[tid] = bi;
    __syncthreads();
    for (int off = 128; off > 0; off >>= 1) {
        if (tid < off) {
            float v2 = sv[tid + off]; int i2 = si[tid + off];
            if (v2 > sv[tid] || (v2 == sv[tid] && i2 < si[tid])) { sv[tid] = v2; si[tid] = i2; }
        }
        __syncthreads();
    }
    int tok = si[0];
    if (tid == 0) toks[t * GENN + p] = tok;
    const float* er = emb + (size_t)tok * D;
    float* brow = buf + ((size_t)t * SEQ + (p + 1)) * D;
    for (int d = tid; d < D; d += 256) brow[d] = er[d];
}

extern "C" void kernel_launch(void* const* d_in, const int* in_sizes, int n_in,
                              void* d_out, int out_size, void* d_ws, size_t ws_size,
                              hipStream_t stream) {
    const float* x0   = (const float*)d_in[0];
    const float* Wq   = (const float*)d_in[1];
    const float* Wk   = (const float*)d_in[2];
    const float* Wv   = (const float*)d_in[3];
    const float* Wo   = (const float*)d_in[4];
    const float* wln1 = (const float*)d_in[5];
    const float* wln2 = (const float*)d_in[6];
    const float* Wg   = (const float*)d_in[7];
    const float* Wu   = (const float*)d_in[8];
    const float* Wd   = (const float*)d_in[9];
    const float* emb  = (const float*)d_in[11];
    const float* Wout = (const float*)d_in[12];
    const float* bout = (const float*)d_in[13];

    float* ws   = (float*)d_ws;
    float* buf  = ws + OFF_BUF;
    float* hT   = ws + OFF_HT;
    float* qb   = ws + OFF_Q;
    float* kcc  = ws + OFF_KC;
    float* vcc  = ws + OFF_VC;
    float* aoT  = ws + OFF_AOT;
    float* xp   = ws + OFF_XP;
    float* h2T  = ws + OFF_H2T;
    float* xoT  = ws + OFF_XOT;
    float* intT = ws + OFF_INT;
    unsigned* Xpk = (unsigned*)(ws + OFF_XPK);
    float* part = ws + OFF_PART;

    size_t availF = (ws_size / 4 > OFF_PART) ? (ws_size / 4 - OFF_PART) : 0;
    auto fitS = [&](int smax, size_t cols, int K) {
        int s = smax;
        while (s > 1 && (size_t)s * cols * TT > availF) s >>= 1;
        while (s > 1 && ((K / s) & 15)) s >>= 1;
        return s;
    };
    const int S_qkv = fitS(16, NQKV, D);
    const int S_wo  = fitS(16, D, D);
    const int S_gu  = fitS(8,  NGU, D);
    const int S_wd  = fitS(16, D, FF);
    const int S_out = fitS(32, VOC, D);
    const int kc_qkv = D / S_qkv;
    const int kc_wo  = D / S_wo;
    const int kc_gu  = D / S_gu;
    const int kc_wd  = FF / S_wd;
    const int kc_out = D / S_out;

    k_init<<<512, 256, 0, stream>>>(x0, buf);
    for (int p = 0; p < GENN; ++p) {
        k_rmsnorm<<<32, 256, 0, stream>>>(buf + (size_t)p * D, SEQ * D, wln1, hT);
        k_pack<<<D / 64, 256, 0, stream>>>(hT, Xpk);
        // fused QKV partial [s][n][TT]: n [0,4096)=Q, [4096,5120)=K, [5120,6144)=V
        k_gemm_mfma<<<128 * S_qkv / 4, 256, 0, stream>>>(Xpk, Wq, part, NQKV, D, 128, kc_qkv, 0);
        k_gemm_mfma<<< 32 * S_qkv / 4, 256, 0, stream>>>(Xpk, Wk, part, NQKV, D, 32, kc_qkv, 4096);
        k_gemm_mfma<<< 32 * S_qkv / 4, 256, 0, stream>>>(Xpk, Wv, part, NQKV, D, 32, kc_qkv, 5120);
        k_qkv_finish<<<448, 256, 0, stream>>>(part, qb, kcc, vcc, p, S_qkv);
        k_attn<<<1024, 64, 0, stream>>>(qb, kcc, vcc, aoT, p);
        k_pack<<<D / 64, 256, 0, stream>>>(aoT, Xpk);
        k_gemm_mfma<<<128 * S_wo / 4, 256, 0, stream>>>(Xpk, Wo, part, D, D, 128, kc_wo, 0);
        k_reduce_o<<<512, 256, 0, stream>>>(part, buf, xp, p, S_wo);
        k_rmsnorm<<<32, 256, 0, stream>>>(xp, D, wln2, h2T);
        k_pack<<<D / 64, 256, 0, stream>>>(h2T, Xpk);
        // fused gate+up partial [s][n][TT]: n [0,FF)=G, [FF,2FF)=U
        k_gemm_mfma<<<448 * S_gu / 4, 256, 0, stream>>>(Xpk, Wg, part, NGU, D, 448, kc_gu, 0);
        k_gemm_mfma<<<448 * S_gu / 4, 256, 0, stream>>>(Xpk, Wu, part, NGU, D, 448, kc_gu, FF);
        k_silu_mul<<<1792, 256, 0, stream>>>(part, intT, S_gu);
        k_pack<<<FF / 64, 256, 0, stream>>>(intT, Xpk);
        k_gemm_mfma<<<128 * S_wd / 4, 256, 0, stream>>>(Xpk, Wd, part, D, FF, 128, kc_wd, 0);
        k_reduce_d<<<512, 256, 0, stream>>>(part, xp, xoT, S_wd);
        k_pack<<<D / 64, 256, 0, stream>>>(xoT, Xpk);
        k_gemm_mfma<<< 32 * S_out / 4, 256, 0, stream>>>(Xpk, Wout, part, VOC, D, 32, kc_out, 0);
        k_head<<<32, 256, 0, stream>>>(part, bout, emb, (int*)d_out, buf, p, S_out);
    }
}